// Round 1
// baseline (1236.389 us; speedup 1.0000x reference)
//
#include <hip/hip_runtime.h>

// GCN: 3x (X@W -> gather/scatter-add with sym-norm -> +b, relu) -> mean-pool -> MLP
// Sizes fixed by the reference.
constexpr int N = 100000;   // nodes
constexpr int E = 1250000;  // edges
constexpr int H = 64;       // hidden (== input dim)
constexpr int G = 64;       // graphs

// deg[i] = in-degree over dst (self loop added later in dinv)
__global__ void deg_kernel(const int* __restrict__ dst, float* __restrict__ deg) {
  int e = blockIdx.x * blockDim.x + threadIdx.x;
  if (e < E) atomicAdd(&deg[dst[e]], 1.0f);
}

// dinv[i] = rsqrt(deg[i] + 1)   (self loop => deg >= 1, no zero check needed)
__global__ void dinv_kernel(float* __restrict__ deg) {
  int i = blockIdx.x * blockDim.x + threadIdx.x;
  if (i < N) deg[i] = rsqrtf(deg[i] + 1.0f);
}

// H = X @ W, X:[N,64] W:[64,64]. 4 rows/block, W staged in LDS.
// Ws[k*64+c]: lane=c stride-1 -> 2-way bank aliasing (free on gfx950).
__global__ void gemm64_kernel(const float* __restrict__ X, const float* __restrict__ W,
                              float* __restrict__ Hout) {
  __shared__ float Ws[64 * 64];
  __shared__ float Xs[4 * 64];
  int tid = threadIdx.x;
  for (int idx = tid; idx < 64 * 64; idx += 256) Ws[idx] = W[idx];
  int row0 = blockIdx.x * 4;
  Xs[tid] = X[row0 * 64 + tid];
  __syncthreads();
  int r = tid >> 6, c = tid & 63;
  float acc = 0.f;
#pragma unroll
  for (int k = 0; k < 64; k++) acc += Xs[r * 64 + k] * Ws[k * 64 + c];
  Hout[(row0 + r) * 64 + c] = acc;
}

// One wave per edge, lane = channel. agg[dst] += h[src] * dinv[src]*dinv[dst]
__global__ void scatter_kernel(const float* __restrict__ Hin, const float* __restrict__ dinv,
                               const int* __restrict__ src, const int* __restrict__ dst,
                               float* __restrict__ agg) {
  int gt = blockIdx.x * blockDim.x + threadIdx.x;
  int e = gt >> 6;
  int lane = gt & 63;
  if (e >= E) return;
  int s = src[e], d = dst[e];
  float nrm = dinv[s] * dinv[d];
  float v = Hin[s * 64 + lane] * nrm;
  atomicAdd(&agg[d * 64 + lane], v);
}

// X_next = relu(agg + H*dinv^2 (self loop) + b). In-place on agg is fine.
__global__ void finalize_kernel(const float* __restrict__ agg, const float* __restrict__ Hin,
                                const float* __restrict__ dinv, const float* __restrict__ b,
                                float* __restrict__ Xout) {
  int idx = blockIdx.x * blockDim.x + threadIdx.x;
  if (idx < N * 64) {
    int node = idx >> 6, c = idx & 63;
    float di = dinv[node];
    float v = agg[idx] + Hin[idx] * di * di + b[c];
    Xout[idx] = fmaxf(v, 0.f);
  }
}

// batch is sorted: each wave scans a contiguous node chunk, flushing one
// atomic row per graph transition (instead of one atomic per node).
__global__ void pool_kernel(const float* __restrict__ X, const int* __restrict__ batch,
                            float* __restrict__ sums, float* __restrict__ cnts) {
  int lane = threadIdx.x & 63;
  int wid = (blockIdx.x * blockDim.x + threadIdx.x) >> 6;
  int nw = (gridDim.x * blockDim.x) >> 6;
  int per = (N + nw - 1) / nw;
  int start = wid * per;
  int end = min(start + per, N);
  float acc = 0.f, cnt = 0.f;
  int cur = -1;
  for (int n = start; n < end; n++) {
    int g = batch[n];
    if (g != cur) {
      if (cur >= 0) {
        atomicAdd(&sums[cur * 64 + lane], acc);
        if (lane == 0) atomicAdd(&cnts[cur], cnt);
      }
      cur = g; acc = 0.f; cnt = 0.f;
    }
    acc += X[n * 64 + lane];
    cnt += 1.f;
  }
  if (cur >= 0) {
    atomicAdd(&sums[cur * 64 + lane], acc);
    if (lane == 0) atomicAdd(&cnts[cur], cnt);
  }
}

// pooled = sums/max(cnts,1); z = relu(pooled@Wc1 + bc1); out = z@Wc2 + bc2
__global__ void classifier_kernel(const float* __restrict__ sums, const float* __restrict__ cnts,
                                  const float* __restrict__ Wc1, const float* __restrict__ bc1,
                                  const float* __restrict__ Wc2, const float* __restrict__ bc2,
                                  float* __restrict__ out) {
  __shared__ float pooled[64 * 64];
  __shared__ float z[64 * 32];
  int tid = threadIdx.x;
  for (int idx = tid; idx < 64 * 64; idx += 256) {
    int g = idx >> 6;
    pooled[idx] = sums[idx] / fmaxf(cnts[g], 1.0f);
  }
  __syncthreads();
  for (int idx = tid; idx < 64 * 32; idx += 256) {
    int g = idx >> 5, j = idx & 31;
    float acc = bc1[j];
#pragma unroll
    for (int c = 0; c < 64; c++) acc += pooled[g * 64 + c] * Wc1[c * 32 + j];
    z[idx] = fmaxf(acc, 0.f);
  }
  __syncthreads();
  for (int idx = tid; idx < 128; idx += 256) {
    int g = idx >> 1, k = idx & 1;
    float acc = bc2[k];
#pragma unroll
    for (int j = 0; j < 32; j++) acc += z[g * 32 + j] * Wc2[j * 2 + k];
    out[idx] = acc;
  }
}

extern "C" void kernel_launch(void* const* d_in, const int* in_sizes, int n_in,
                              void* d_out, int out_size, void* d_ws, size_t ws_size,
                              hipStream_t stream) {
  const float* x   = (const float*)d_in[0];
  const float* W1  = (const float*)d_in[1];
  const float* b1  = (const float*)d_in[2];
  const float* W2  = (const float*)d_in[3];
  const float* b2  = (const float*)d_in[4];
  const float* W3  = (const float*)d_in[5];
  const float* b3  = (const float*)d_in[6];
  const float* Wc1 = (const float*)d_in[7];
  const float* bc1 = (const float*)d_in[8];
  const float* Wc2 = (const float*)d_in[9];
  const float* bc2 = (const float*)d_in[10];
  const int* ei    = (const int*)d_in[11];   // [2, E] flat: row0 = src, row1 = dst
  const int* batch = (const int*)d_in[12];
  const int* src  = ei;
  const int* dstp = ei + E;

  char* ws = (char*)d_ws;
  size_t off = 0;
  auto alloc = [&](size_t bytes) {
    char* p = ws + off;
    off += (bytes + 255) & ~size_t(255);
    return p;
  };
  float* dinv = (float*)alloc((size_t)N * 4);
  float* B0 = (float*)alloc((size_t)N * 64 * 4);   // H (X@W) each layer
  float* B1 = (float*)alloc((size_t)N * 64 * 4);   // agg L1/L3
  float* B2 = (float*)alloc((size_t)N * 64 * 4);   // agg L2
  float* sums = (float*)alloc((size_t)(G * 64 + G) * 4);
  float* cnts = sums + G * 64;

  // degrees -> dinv
  hipMemsetAsync(dinv, 0, (size_t)N * 4, stream);
  deg_kernel<<<(E + 255) / 256, 256, 0, stream>>>(dstp, dinv);
  dinv_kernel<<<(N + 255) / 256, 256, 0, stream>>>(dinv);

  const float* Xc = x;
  const float* Wl[3] = {W1, W2, W3};
  const float* bl[3] = {b1, b2, b3};
  float* aggbuf[3] = {B1, B2, B1};
  for (int l = 0; l < 3; l++) {
    float* Hb = B0;
    float* agg = aggbuf[l];
    gemm64_kernel<<<N / 4, 256, 0, stream>>>(Xc, Wl[l], Hb);
    hipMemsetAsync(agg, 0, (size_t)N * 64 * 4, stream);
    scatter_kernel<<<(E * 64 + 255) / 256, 256, 0, stream>>>(Hb, dinv, src, dstp, agg);
    finalize_kernel<<<(N * 64 + 255) / 256, 256, 0, stream>>>(agg, Hb, dinv, bl[l], agg);
    Xc = agg;
  }

  hipMemsetAsync(sums, 0, (size_t)(G * 64 + G) * 4, stream);
  pool_kernel<<<256, 256, 0, stream>>>(Xc, batch, sums, cnts);
  classifier_kernel<<<1, 256, 0, stream>>>(sums, cnts, Wc1, bc1, Wc2, bc2, (float*)d_out);
}

// Round 2
// 639.858 us; speedup vs baseline: 1.9323x; 1.9323x over previous
//
#include <hip/hip_runtime.h>

// GCN: CSR-based pull aggregation (no fp32 atomics in the hot path).
// Per launch: deg histogram -> exclusive scan -> CSR fill, then
// 3x (X@W -> per-node gather-accumulate fused with norm/selfloop/bias/relu),
// then mean-pool -> classifier MLP.
constexpr int N = 100000;   // nodes
constexpr int E = 1250000;  // edges
constexpr int G = 64;       // graphs

// ---- CSR build -------------------------------------------------------------

__global__ void deg_kernel(const int* __restrict__ dst, int* __restrict__ deg) {
  int e = blockIdx.x * blockDim.x + threadIdx.x;
  if (e < E) atomicAdd(&deg[dst[e]], 1);
}

// dinv[i] = rsqrt(deg[i] + 1)  (+1 = self loop)
__global__ void dinv_kernel(const int* __restrict__ deg, float* __restrict__ dinv) {
  int i = blockIdx.x * blockDim.x + threadIdx.x;
  if (i < N) dinv[i] = rsqrtf((float)deg[i] + 1.0f);
}

// Exclusive scan, stage 1: 1024 elements/block (4/thread), LDS Hillis-Steele.
__global__ void scan1_kernel(const int* __restrict__ deg, int* __restrict__ rowptr,
                             int* __restrict__ blocksum) {
  __shared__ int s[256];
  int tid = threadIdx.x;
  int base = blockIdx.x * 1024 + tid * 4;
  int d0 = (base + 0 < N) ? deg[base + 0] : 0;
  int d1 = (base + 1 < N) ? deg[base + 1] : 0;
  int d2 = (base + 2 < N) ? deg[base + 2] : 0;
  int d3 = (base + 3 < N) ? deg[base + 3] : 0;
  int t = d0 + d1 + d2 + d3;
  s[tid] = t;
  __syncthreads();
  for (int off = 1; off < 256; off <<= 1) {
    int v = (tid >= off) ? s[tid - off] : 0;
    __syncthreads();
    s[tid] += v;
    __syncthreads();
  }
  int excl = s[tid] - t;
  if (base + 0 < N) rowptr[base + 0] = excl;
  if (base + 1 < N) rowptr[base + 1] = excl + d0;
  if (base + 2 < N) rowptr[base + 2] = excl + d0 + d1;
  if (base + 3 < N) rowptr[base + 3] = excl + d0 + d1 + d2;
  if (tid == 255) blocksum[blockIdx.x] = s[255];
}

// Stage 2: add prefix of blocksums (<=98 of them; serial per block is trivial).
__global__ void scan2_kernel(int* __restrict__ rowptr, const int* __restrict__ blocksum) {
  __shared__ int off;
  if (threadIdx.x == 0) {
    int o = 0;
    for (int i = 0; i < (int)blockIdx.x; i++) o += blocksum[i];
    off = o;
  }
  __syncthreads();
  int base = blockIdx.x * 1024 + threadIdx.x * 4;
#pragma unroll
  for (int j = 0; j < 4; j++)
    if (base + j < N) rowptr[base + j] += off;
}

// Fill CSR: csr[rowptr[d] + slot] = src  (slot via int atomic; order irrelevant)
__global__ void fill_kernel(const int* __restrict__ src, const int* __restrict__ dst,
                            const int* __restrict__ rowptr, int* __restrict__ fillcnt,
                            int* __restrict__ csr) {
  int e = blockIdx.x * blockDim.x + threadIdx.x;
  if (e < E) {
    int d = dst[e];
    int pos = rowptr[d] + atomicAdd(&fillcnt[d], 1);
    csr[pos] = src[e];
  }
}

// ---- dense layers ----------------------------------------------------------

// H = X @ W, X:[N,64] W:[64,64]. 4 rows/block, W staged in LDS.
__global__ void gemm64_kernel(const float* __restrict__ X, const float* __restrict__ W,
                              float* __restrict__ Hout) {
  __shared__ float Ws[64 * 64];
  __shared__ float Xs[4 * 64];
  int tid = threadIdx.x;
  for (int idx = tid; idx < 64 * 64; idx += 256) Ws[idx] = W[idx];
  int row0 = blockIdx.x * 4;
  Xs[tid] = X[row0 * 64 + tid];
  __syncthreads();
  int r = tid >> 6, c = tid & 63;
  float acc = 0.f;
#pragma unroll
  for (int k = 0; k < 64; k++) acc += Xs[r * 64 + k] * Ws[k * 64 + c];
  Hout[(row0 + r) * 64 + c] = acc;
}

// One wave per dst node, lane = channel. Pull over incoming edges:
//   Xout[d] = relu( dinv[d] * sum_s H[s]*dinv[s] + H[d]*dinv[d]^2 + b )
// 4-edge unroll keeps 4 independent gathers in flight per wave.
__global__ void agg_kernel(const float* __restrict__ Hin, const float* __restrict__ dinv,
                           const int* __restrict__ rowptr, const int* __restrict__ deg,
                           const int* __restrict__ csr, const float* __restrict__ b,
                           float* __restrict__ Xout) {
  int node = (blockIdx.x * blockDim.x + threadIdx.x) >> 6;
  int lane = threadIdx.x & 63;
  if (node >= N) return;
  int start = rowptr[node];
  int cnt = deg[node];
  float acc = 0.f;
  int k = 0;
  for (; k + 4 <= cnt; k += 4) {
    int s0 = csr[start + k + 0];
    int s1 = csr[start + k + 1];
    int s2 = csr[start + k + 2];
    int s3 = csr[start + k + 3];
    float w0 = dinv[s0], w1 = dinv[s1], w2 = dinv[s2], w3 = dinv[s3];
    float h0 = Hin[s0 * 64 + lane];
    float h1 = Hin[s1 * 64 + lane];
    float h2 = Hin[s2 * 64 + lane];
    float h3 = Hin[s3 * 64 + lane];
    acc += h0 * w0 + h1 * w1 + h2 * w2 + h3 * w3;
  }
  for (; k < cnt; k++) {
    int s = csr[start + k];
    acc += Hin[s * 64 + lane] * dinv[s];
  }
  float di = dinv[node];
  float v = acc * di + Hin[node * 64 + lane] * di * di + b[lane];
  Xout[node * 64 + lane] = fmaxf(v, 0.f);
}

// ---- pool + classifier -----------------------------------------------------

__global__ void pool_kernel(const float* __restrict__ X, const int* __restrict__ batch,
                            float* __restrict__ sums, float* __restrict__ cnts) {
  int lane = threadIdx.x & 63;
  int wid = (blockIdx.x * blockDim.x + threadIdx.x) >> 6;
  int nw = (gridDim.x * blockDim.x) >> 6;
  int per = (N + nw - 1) / nw;
  int start = wid * per;
  int end = min(start + per, N);
  float acc = 0.f, cnt = 0.f;
  int cur = -1;
  for (int n = start; n < end; n++) {
    int g = batch[n];
    if (g != cur) {
      if (cur >= 0) {
        atomicAdd(&sums[cur * 64 + lane], acc);
        if (lane == 0) atomicAdd(&cnts[cur], cnt);
      }
      cur = g; acc = 0.f; cnt = 0.f;
    }
    acc += X[n * 64 + lane];
    cnt += 1.f;
  }
  if (cur >= 0) {
    atomicAdd(&sums[cur * 64 + lane], acc);
    if (lane == 0) atomicAdd(&cnts[cur], cnt);
  }
}

__global__ void classifier_kernel(const float* __restrict__ sums, const float* __restrict__ cnts,
                                  const float* __restrict__ Wc1, const float* __restrict__ bc1,
                                  const float* __restrict__ Wc2, const float* __restrict__ bc2,
                                  float* __restrict__ out) {
  __shared__ float pooled[64 * 64];
  __shared__ float z[64 * 32];
  int tid = threadIdx.x;
  for (int idx = tid; idx < 64 * 64; idx += 256) {
    int g = idx >> 6;
    pooled[idx] = sums[idx] / fmaxf(cnts[g], 1.0f);
  }
  __syncthreads();
  for (int idx = tid; idx < 64 * 32; idx += 256) {
    int g = idx >> 5, j = idx & 31;
    float acc = bc1[j];
#pragma unroll
    for (int c = 0; c < 64; c++) acc += pooled[g * 64 + c] * Wc1[c * 32 + j];
    z[idx] = fmaxf(acc, 0.f);
  }
  __syncthreads();
  for (int idx = tid; idx < 128; idx += 256) {
    int g = idx >> 1, k = idx & 1;
    float acc = bc2[k];
#pragma unroll
    for (int j = 0; j < 32; j++) acc += z[g * 32 + j] * Wc2[j * 2 + k];
    out[idx] = acc;
  }
}

// ---- launch ----------------------------------------------------------------

extern "C" void kernel_launch(void* const* d_in, const int* in_sizes, int n_in,
                              void* d_out, int out_size, void* d_ws, size_t ws_size,
                              hipStream_t stream) {
  const float* x   = (const float*)d_in[0];
  const float* W1  = (const float*)d_in[1];
  const float* b1  = (const float*)d_in[2];
  const float* W2  = (const float*)d_in[3];
  const float* b2  = (const float*)d_in[4];
  const float* W3  = (const float*)d_in[5];
  const float* b3  = (const float*)d_in[6];
  const float* Wc1 = (const float*)d_in[7];
  const float* bc1 = (const float*)d_in[8];
  const float* Wc2 = (const float*)d_in[9];
  const float* bc2 = (const float*)d_in[10];
  const int* ei    = (const int*)d_in[11];   // [2, E]: row0 = src, row1 = dst
  const int* batch = (const int*)d_in[12];
  const int* src  = ei;
  const int* dstp = ei + E;

  char* ws = (char*)d_ws;
  size_t off = 0;
  auto alloc = [&](size_t bytes) {
    char* p = ws + off;
    off += (bytes + 255) & ~size_t(255);
    return p;
  };
  int*   deg      = (int*)alloc((size_t)N * 4);
  int*   rowptr   = (int*)alloc((size_t)N * 4);
  int*   fillcnt  = (int*)alloc((size_t)N * 4);
  int*   csr      = (int*)alloc((size_t)E * 4);
  int*   blocksum = (int*)alloc(128 * 4);
  float* dinv     = (float*)alloc((size_t)N * 4);
  float* B0 = (float*)alloc((size_t)N * 64 * 4);   // H = X@W each layer
  float* B1 = (float*)alloc((size_t)N * 64 * 4);   // X_next (reused in place)
  float* sums = (float*)alloc((size_t)(G * 64 + G) * 4);
  float* cnts = sums + G * 64;

  constexpr int SCAN_BLOCKS = (N + 1023) / 1024;   // 98

  hipMemsetAsync(deg, 0, (size_t)N * 4, stream);
  hipMemsetAsync(fillcnt, 0, (size_t)N * 4, stream);
  hipMemsetAsync(sums, 0, (size_t)(G * 64 + G) * 4, stream);

  deg_kernel<<<(E + 255) / 256, 256, 0, stream>>>(dstp, deg);
  dinv_kernel<<<(N + 255) / 256, 256, 0, stream>>>(deg, dinv);
  scan1_kernel<<<SCAN_BLOCKS, 256, 0, stream>>>(deg, rowptr, blocksum);
  scan2_kernel<<<SCAN_BLOCKS, 256, 0, stream>>>(rowptr, blocksum);
  fill_kernel<<<(E + 255) / 256, 256, 0, stream>>>(src, dstp, rowptr, fillcnt, csr);

  const float* Xc = x;
  const float* Wl[3] = {W1, W2, W3};
  const float* bl[3] = {b1, b2, b3};
  for (int l = 0; l < 3; l++) {
    gemm64_kernel<<<N / 4, 256, 0, stream>>>(Xc, Wl[l], B0);
    agg_kernel<<<(N * 64 + 255) / 256, 256, 0, stream>>>(B0, dinv, rowptr, deg, csr, bl[l], B1);
    Xc = B1;
  }

  pool_kernel<<<256, 256, 0, stream>>>(Xc, batch, sums, cnts);
  classifier_kernel<<<1, 256, 0, stream>>>(sums, cnts, Wc1, bc1, Wc2, bc2, (float*)d_out);
}

// Round 3
// 494.982 us; speedup vs baseline: 2.4978x; 1.2927x over previous
//
#include <hip/hip_runtime.h>

// GCN via single-pass fixed-stride bucket CSR (K=40 slots/node + exact overflow
// path), dinv folded into GEMM epilogue, pull-mode aggregation (no fp32 atomics).
constexpr int N = 100000;   // nodes
constexpr int E = 1250000;  // edges
constexpr int G = 64;       // graphs
constexpr int K = 40;       // bucket capacity (Poisson(12.5): P(deg>40) ~ 1e-10)

// ---- graph build: one pass over edges --------------------------------------
// cnt[d] = in-degree (exact, even past K). csr[d*K+slot] = src for slot < K.
// Overflow edges appended to ovf (exact correctness for any degree skew).
__global__ void build_kernel(const int* __restrict__ src, const int* __restrict__ dst,
                             int* __restrict__ cnt, int* __restrict__ csr,
                             int* __restrict__ ovf, int* __restrict__ ovf_cnt) {
  int e = blockIdx.x * blockDim.x + threadIdx.x;
  if (e >= E) return;
  int d = dst[e], s = src[e];
  int slot = atomicAdd(&cnt[d], 1);
  if (slot < K) {
    csr[d * K + slot] = s;
  } else {
    int p = atomicAdd(ovf_cnt, 1);
    ovf[2 * p] = s;
    ovf[2 * p + 1] = d;
  }
}

// ---- Hs = (X @ W) * dinv[row], 16 rows/block -------------------------------
__global__ void gemm_premul_kernel(const float* __restrict__ X, const float* __restrict__ W,
                                   const int* __restrict__ cnt, float* __restrict__ Hs) {
  __shared__ float Ws[64 * 64];
  __shared__ float Xs[16 * 64];
  int tid = threadIdx.x;
  for (int idx = tid; idx < 64 * 64; idx += 256) Ws[idx] = W[idx];
  int row0 = blockIdx.x * 16;
  for (int idx = tid; idx < 16 * 64; idx += 256) Xs[idx] = X[row0 * 64 + idx];
  __syncthreads();
  int r0 = tid >> 6, c = tid & 63;
  float acc0 = 0.f, acc1 = 0.f, acc2 = 0.f, acc3 = 0.f;
#pragma unroll
  for (int k = 0; k < 64; k++) {
    float w = Ws[k * 64 + c];                 // stride-1: 2-way alias, free
    acc0 += Xs[(r0 +  0) * 64 + k] * w;       // wave-broadcast reads
    acc1 += Xs[(r0 +  4) * 64 + k] * w;
    acc2 += Xs[(r0 +  8) * 64 + k] * w;
    acc3 += Xs[(r0 + 12) * 64 + k] * w;
  }
  float a[4] = {acc0, acc1, acc2, acc3};
#pragma unroll
  for (int j = 0; j < 4; j++) {
    int r = row0 + r0 + j * 4;
    float di = rsqrtf((float)cnt[r] + 1.0f);
    Hs[r * 64 + c] = a[j] * di;
  }
}

// ---- pull aggregation, one wave per node, lane = channel -------------------
//   Xout[d] = relu( dinv[d]*( sum_s Hs[s] + Hs[d] ) + b )   (Hs pre-scaled by dinv[src])
__global__ void agg_kernel(const float* __restrict__ Hs, const int* __restrict__ cnt,
                           const int* __restrict__ csr, const int* __restrict__ ovf,
                           const int* __restrict__ ovf_cnt, const float* __restrict__ b,
                           float* __restrict__ Xout) {
  int node = (blockIdx.x * blockDim.x + threadIdx.x) >> 6;
  int lane = threadIdx.x & 63;
  if (node >= N) return;
  int c = cnt[node];
  int m = min(c, K);
  const int* bucket = csr + node * K;
  float acc = 0.f;
  int k = 0;
  for (; k + 4 <= m; k += 4) {
    int s0 = bucket[k + 0], s1 = bucket[k + 1], s2 = bucket[k + 2], s3 = bucket[k + 3];
    float h0 = Hs[s0 * 64 + lane];
    float h1 = Hs[s1 * 64 + lane];
    float h2 = Hs[s2 * 64 + lane];
    float h3 = Hs[s3 * 64 + lane];
    acc += h0 + h1 + h2 + h3;
  }
  for (; k < m; k++) acc += Hs[bucket[k] * 64 + lane];
  int on = *ovf_cnt;                       // 0 in practice; exact fallback
  if (on > 0) {
    for (int j = 0; j < on; j++)
      if (ovf[2 * j + 1] == node) acc += Hs[ovf[2 * j] * 64 + lane];
  }
  float di = rsqrtf((float)c + 1.0f);
  float v = di * (acc + Hs[node * 64 + lane]) + b[lane];
  Xout[node * 64 + lane] = fmaxf(v, 0.f);
}

// ---- pool + classifier -----------------------------------------------------
__global__ void pool_kernel(const float* __restrict__ X, const int* __restrict__ batch,
                            float* __restrict__ sums, float* __restrict__ cnts) {
  int lane = threadIdx.x & 63;
  int wid = (blockIdx.x * blockDim.x + threadIdx.x) >> 6;
  int nw = (gridDim.x * blockDim.x) >> 6;
  int per = (N + nw - 1) / nw;
  int start = wid * per;
  int end = min(start + per, N);
  float acc = 0.f, cnt = 0.f;
  int cur = -1;
  for (int n = start; n < end; n++) {
    int g = batch[n];
    if (g != cur) {
      if (cur >= 0) {
        atomicAdd(&sums[cur * 64 + lane], acc);
        if (lane == 0) atomicAdd(&cnts[cur], cnt);
      }
      cur = g; acc = 0.f; cnt = 0.f;
    }
    acc += X[n * 64 + lane];
    cnt += 1.f;
  }
  if (cur >= 0) {
    atomicAdd(&sums[cur * 64 + lane], acc);
    if (lane == 0) atomicAdd(&cnts[cur], cnt);
  }
}

__global__ void classifier_kernel(const float* __restrict__ sums, const float* __restrict__ cnts,
                                  const float* __restrict__ Wc1, const float* __restrict__ bc1,
                                  const float* __restrict__ Wc2, const float* __restrict__ bc2,
                                  float* __restrict__ out) {
  __shared__ float pooled[64 * 64];
  __shared__ float z[64 * 32];
  int tid = threadIdx.x;
  for (int idx = tid; idx < 64 * 64; idx += 256) {
    int g = idx >> 6;
    pooled[idx] = sums[idx] / fmaxf(cnts[g], 1.0f);
  }
  __syncthreads();
  for (int idx = tid; idx < 64 * 32; idx += 256) {
    int g = idx >> 5, j = idx & 31;
    float acc = bc1[j];
#pragma unroll
    for (int c = 0; c < 64; c++) acc += pooled[g * 64 + c] * Wc1[c * 32 + j];
    z[idx] = fmaxf(acc, 0.f);
  }
  __syncthreads();
  for (int idx = tid; idx < 128; idx += 256) {
    int g = idx >> 1, k = idx & 1;
    float acc = bc2[k];
#pragma unroll
    for (int j = 0; j < 32; j++) acc += z[g * 32 + j] * Wc2[j * 2 + k];
    out[idx] = acc;
  }
}

// ---- launch ----------------------------------------------------------------
extern "C" void kernel_launch(void* const* d_in, const int* in_sizes, int n_in,
                              void* d_out, int out_size, void* d_ws, size_t ws_size,
                              hipStream_t stream) {
  const float* x   = (const float*)d_in[0];
  const float* W1  = (const float*)d_in[1];
  const float* b1  = (const float*)d_in[2];
  const float* W2  = (const float*)d_in[3];
  const float* b2  = (const float*)d_in[4];
  const float* W3  = (const float*)d_in[5];
  const float* b3  = (const float*)d_in[6];
  const float* Wc1 = (const float*)d_in[7];
  const float* bc1 = (const float*)d_in[8];
  const float* Wc2 = (const float*)d_in[9];
  const float* bc2 = (const float*)d_in[10];
  const int* ei    = (const int*)d_in[11];   // [2, E]: row0 = src, row1 = dst
  const int* batch = (const int*)d_in[12];
  const int* src  = ei;
  const int* dstp = ei + E;

  char* ws = (char*)d_ws;
  size_t off = 0;
  auto alloc = [&](size_t bytes) {
    char* p = ws + off;
    off += (bytes + 255) & ~size_t(255);
    return p;
  };
  int*   cnt  = (int*)alloc((size_t)(N + 1) * 4);      // +1: overflow counter
  int*   csr  = (int*)alloc((size_t)N * K * 4);        // 16 MB buckets
  int*   ovf  = (int*)alloc((size_t)E * 2 * 4);        // exact worst-case spill
  float* B0   = (float*)alloc((size_t)N * 64 * 4);     // Hs each layer
  float* B1   = (float*)alloc((size_t)N * 64 * 4);     // X_next (in place reuse)
  float* sums = (float*)alloc((size_t)(G * 64 + G) * 4);
  float* cnts = sums + G * 64;
  int* ovf_cnt = cnt + N;

  hipMemsetAsync(cnt, 0, (size_t)(N + 1) * 4, stream);
  hipMemsetAsync(sums, 0, (size_t)(G * 64 + G) * 4, stream);

  build_kernel<<<(E + 255) / 256, 256, 0, stream>>>(src, dstp, cnt, csr, ovf, ovf_cnt);

  const float* Xc = x;
  const float* Wl[3] = {W1, W2, W3};
  const float* bl[3] = {b1, b2, b3};
  for (int l = 0; l < 3; l++) {
    gemm_premul_kernel<<<N / 16, 256, 0, stream>>>(Xc, Wl[l], cnt, B0);
    agg_kernel<<<(N * 64 + 255) / 256, 256, 0, stream>>>(B0, cnt, csr, ovf, ovf_cnt, bl[l], B1);
    Xc = B1;
  }

  pool_kernel<<<512, 256, 0, stream>>>(Xc, batch, sums, cnts);
  classifier_kernel<<<1, 256, 0, stream>>>(sums, cnts, Wc1, bc1, Wc2, bc2, (float*)d_out);
}

// Round 4
// 437.651 us; speedup vs baseline: 2.8251x; 1.1310x over previous
//
#include <hip/hip_runtime.h>

// GCN: single-pass bucket CSR (K=40 + exact overflow), dinv folded into GEMM
// epilogue, pull aggregation with float4 gathers (4 edges in flight/wave,
// bucket indices preloaded into registers and distributed via shuffle).
constexpr int N = 100000;   // nodes
constexpr int E = 1250000;  // edges
constexpr int G = 64;       // graphs
constexpr int K = 40;       // bucket capacity (Poisson(12.5): P(deg>40) ~ 1e-10)

// ---- graph build: one pass over edges --------------------------------------
__global__ void build_kernel(const int* __restrict__ src, const int* __restrict__ dst,
                             int* __restrict__ cnt, int* __restrict__ csr,
                             int* __restrict__ ovf, int* __restrict__ ovf_cnt) {
  int e = blockIdx.x * blockDim.x + threadIdx.x;
  if (e >= E) return;
  int d = dst[e], s = src[e];
  int slot = atomicAdd(&cnt[d], 1);
  if (slot < K) {
    __builtin_nontemporal_store(s, &csr[d * K + slot]);
  } else {
    int p = atomicAdd(ovf_cnt, 1);
    ovf[2 * p] = s;
    ovf[2 * p + 1] = d;
  }
}

// ---- Hs = (X @ W) * dinv[row], 32 rows/block, float4 throughout ------------
constexpr int XS_STRIDE = 68;  // pad: bank(r*68) = 4r%32 -> only 2-way alias (free)
__global__ void gemm_premul_kernel(const float* __restrict__ X, const float* __restrict__ W,
                                   const int* __restrict__ cnt, float* __restrict__ Hs) {
  __shared__ float Ws[64 * 64];
  __shared__ float Xs[32 * XS_STRIDE];
  int tid = threadIdx.x;
  const float4* W4 = (const float4*)W;
#pragma unroll
  for (int j = 0; j < 4; j++)
    ((float4*)Ws)[tid + j * 256] = W4[tid + j * 256];
  int row0 = blockIdx.x * 32;
  const float4* X4 = (const float4*)(X + row0 * 64);
#pragma unroll
  for (int j = 0; j < 2; j++) {
    int idx = tid + j * 256;          // float4 index within 32x64 tile
    int r = idx >> 4, q = idx & 15;   // row, quad-within-row
    *((float4*)&Xs[r * XS_STRIDE + q * 4]) = X4[idx];
  }
  __syncthreads();
  int r0 = tid >> 4;                  // 0..15 (handles rows r0 and r0+16)
  int c = (tid & 15) * 4;             // channel quad
  float4 acc0 = {0, 0, 0, 0}, acc1 = {0, 0, 0, 0};
#pragma unroll
  for (int k = 0; k < 64; k++) {
    float4 w = *((const float4*)&Ws[k * 64 + c]);   // 2-way alias, free
    float xa = Xs[r0 * XS_STRIDE + k];
    float xb = Xs[(r0 + 16) * XS_STRIDE + k];
    acc0.x += xa * w.x; acc0.y += xa * w.y; acc0.z += xa * w.z; acc0.w += xa * w.w;
    acc1.x += xb * w.x; acc1.y += xb * w.y; acc1.z += xb * w.z; acc1.w += xb * w.w;
  }
  int ra = row0 + r0, rb = ra + 16;
  float da = rsqrtf((float)cnt[ra] + 1.0f);
  float db = rsqrtf((float)cnt[rb] + 1.0f);
  acc0.x *= da; acc0.y *= da; acc0.z *= da; acc0.w *= da;
  acc1.x *= db; acc1.y *= db; acc1.z *= db; acc1.w *= db;
  *((float4*)&Hs[ra * 64 + c]) = acc0;
  *((float4*)&Hs[rb * 64 + c]) = acc1;
}

// ---- pull aggregation: one wave/node, 4 edges in flight via lane groups ----
//   Xout[d] = relu( dinv[d]*( sum_s Hs[s] + Hs[d] ) + b )  (Hs pre-scaled by dinv[src])
__global__ void agg_kernel(const float* __restrict__ Hs, const int* __restrict__ cnt,
                           const int* __restrict__ csr, const int* __restrict__ ovf,
                           const int* __restrict__ ovf_cnt, const float* __restrict__ b,
                           float* __restrict__ Xout) {
  int node = (blockIdx.x * blockDim.x + threadIdx.x) >> 6;
  int lane = threadIdx.x & 63;
  if (node >= N) return;
  int g = lane >> 4;        // edge group 0..3
  int i = lane & 15;        // channel quad 0..15
  int c = cnt[node];
  int m = min(c, K);
  // preload all bucket indices (m <= 40 < 64): lane l holds bucket[l]
  int sv = (lane < m) ? csr[node * K + lane] : node;
  const float4* H4 = (const float4*)Hs;
  float4 acc = {0, 0, 0, 0};
  for (int k = 0; k < m; k += 4) {
    int j = k + g;
    int s = __shfl(sv, j);                  // edge src for this group
    bool valid = j < m;
    float4 h = H4[(valid ? s : node) * 16 + i];
    if (valid) { acc.x += h.x; acc.y += h.y; acc.z += h.z; acc.w += h.w; }
  }
  // rare exact overflow path (deg > K)
  int on = *ovf_cnt;
  if (on > 0 && g == 0) {
    for (int j = 0; j < on; j++)
      if (ovf[2 * j + 1] == node) {
        float4 h = H4[ovf[2 * j] * 16 + i];
        acc.x += h.x; acc.y += h.y; acc.z += h.z; acc.w += h.w;
      }
  }
  // combine the 4 edge groups (butterfly over lane^16, lane^32)
#pragma unroll
  for (int off = 16; off < 64; off <<= 1) {
    acc.x += __shfl_xor(acc.x, off);
    acc.y += __shfl_xor(acc.y, off);
    acc.z += __shfl_xor(acc.z, off);
    acc.w += __shfl_xor(acc.w, off);
  }
  if (g == 0) {
    float4 self = H4[node * 16 + i];
    float4 bb = ((const float4*)b)[i];
    float di = rsqrtf((float)c + 1.0f);
    float4 o;
    o.x = fmaxf(di * (acc.x + self.x) + bb.x, 0.f);
    o.y = fmaxf(di * (acc.y + self.y) + bb.y, 0.f);
    o.z = fmaxf(di * (acc.z + self.z) + bb.z, 0.f);
    o.w = fmaxf(di * (acc.w + self.w) + bb.w, 0.f);
    ((float4*)Xout)[node * 16 + i] = o;
  }
}

// ---- pool + classifier -----------------------------------------------------
__global__ void pool_kernel(const float* __restrict__ X, const int* __restrict__ batch,
                            float* __restrict__ sums, float* __restrict__ cnts) {
  int lane = threadIdx.x & 63;
  int wid = (blockIdx.x * blockDim.x + threadIdx.x) >> 6;
  int nw = (gridDim.x * blockDim.x) >> 6;
  int per = (N + nw - 1) / nw;
  int start = wid * per;
  int end = min(start + per, N);
  float acc = 0.f, cnt = 0.f;
  int cur = -1;
  for (int n = start; n < end; n++) {
    int g = batch[n];
    if (g != cur) {
      if (cur >= 0) {
        atomicAdd(&sums[cur * 64 + lane], acc);
        if (lane == 0) atomicAdd(&cnts[cur], cnt);
      }
      cur = g; acc = 0.f; cnt = 0.f;
    }
    acc += X[n * 64 + lane];
    cnt += 1.f;
  }
  if (cur >= 0) {
    atomicAdd(&sums[cur * 64 + lane], acc);
    if (lane == 0) atomicAdd(&cnts[cur], cnt);
  }
}

__global__ void classifier_kernel(const float* __restrict__ sums, const float* __restrict__ cnts,
                                  const float* __restrict__ Wc1, const float* __restrict__ bc1,
                                  const float* __restrict__ Wc2, const float* __restrict__ bc2,
                                  float* __restrict__ out) {
  __shared__ float pooled[64 * 64];
  __shared__ float z[64 * 32];
  int tid = threadIdx.x;
  for (int idx = tid; idx < 64 * 64; idx += 256) {
    int g = idx >> 6;
    pooled[idx] = sums[idx] / fmaxf(cnts[g], 1.0f);
  }
  __syncthreads();
  for (int idx = tid; idx < 64 * 32; idx += 256) {
    int g = idx >> 5, j = idx & 31;
    float acc = bc1[j];
#pragma unroll
    for (int c = 0; c < 64; c++) acc += pooled[g * 64 + c] * Wc1[c * 32 + j];
    z[idx] = fmaxf(acc, 0.f);
  }
  __syncthreads();
  for (int idx = tid; idx < 128; idx += 256) {
    int g = idx >> 1, k = idx & 1;
    float acc = bc2[k];
#pragma unroll
    for (int j = 0; j < 32; j++) acc += z[g * 32 + j] * Wc2[j * 2 + k];
    out[idx] = acc;
  }
}

// ---- launch ----------------------------------------------------------------
extern "C" void kernel_launch(void* const* d_in, const int* in_sizes, int n_in,
                              void* d_out, int out_size, void* d_ws, size_t ws_size,
                              hipStream_t stream) {
  const float* x   = (const float*)d_in[0];
  const float* W1  = (const float*)d_in[1];
  const float* b1  = (const float*)d_in[2];
  const float* W2  = (const float*)d_in[3];
  const float* b2  = (const float*)d_in[4];
  const float* W3  = (const float*)d_in[5];
  const float* b3  = (const float*)d_in[6];
  const float* Wc1 = (const float*)d_in[7];
  const float* bc1 = (const float*)d_in[8];
  const float* Wc2 = (const float*)d_in[9];
  const float* bc2 = (const float*)d_in[10];
  const int* ei    = (const int*)d_in[11];   // [2, E]: row0 = src, row1 = dst
  const int* batch = (const int*)d_in[12];
  const int* src  = ei;
  const int* dstp = ei + E;

  char* ws = (char*)d_ws;
  size_t off = 0;
  auto alloc = [&](size_t bytes) {
    char* p = ws + off;
    off += (bytes + 255) & ~size_t(255);
    return p;
  };
  int*   cnt  = (int*)alloc((size_t)(N + 1) * 4);
  int*   csr  = (int*)alloc((size_t)N * K * 4);
  int*   ovf  = (int*)alloc((size_t)E * 2 * 4);
  float* B0   = (float*)alloc((size_t)N * 64 * 4);
  float* B1   = (float*)alloc((size_t)N * 64 * 4);
  float* sums = (float*)alloc((size_t)(G * 64 + G) * 4);
  float* cnts = sums + G * 64;
  int* ovf_cnt = cnt + N;

  hipMemsetAsync(cnt, 0, (size_t)(N + 1) * 4, stream);
  hipMemsetAsync(sums, 0, (size_t)(G * 64 + G) * 4, stream);

  build_kernel<<<(E + 255) / 256, 256, 0, stream>>>(src, dstp, cnt, csr, ovf, ovf_cnt);

  const float* Xc = x;
  const float* Wl[3] = {W1, W2, W3};
  const float* bl[3] = {b1, b2, b3};
  for (int l = 0; l < 3; l++) {
    gemm_premul_kernel<<<N / 32 + 1, 256, 0, stream>>>(Xc, Wl[l], cnt, B0);
    agg_kernel<<<(N * 64 + 255) / 256, 256, 0, stream>>>(B0, cnt, csr, ovf, ovf_cnt, bl[l], B1);
    Xc = B1;
  }

  pool_kernel<<<512, 256, 0, stream>>>(Xc, batch, sums, cnts);
  classifier_kernel<<<1, 256, 0, stream>>>(sums, cnts, Wc1, bc1, Wc2, bc2, (float*)d_out);
}